// Round 1
// baseline (849.671 us; speedup 1.0000x reference)
//
#include <hip/hip_runtime.h>

#define NTOK 2048
#define DIM  2048
#define HID  1024
#define NEXP 8
#define NE   9              // 8 routed + 1 shared
#define KP   (NE * HID)     // 9216

typedef float f32x4 __attribute__((ext_vector_type(4)));
typedef __bf16 bf16x8 __attribute__((ext_vector_type(8)));

__device__ __forceinline__ unsigned int f2bf(float f) {
    unsigned int u = __float_as_uint(f);
    u += 0x7FFFu + ((u >> 16) & 1u);   // RNE
    return u >> 16;
}
__device__ __forceinline__ float bf2f(unsigned int h) {
    return __uint_as_float(h << 16);
}
__device__ __forceinline__ int pack2(float a, float b) {
    return (int)(f2bf(a) | (f2bf(b) << 16));
}

// ---------------- cast x to bf16 ----------------
__global__ __launch_bounds__(256) void cast_x_kernel(
    const float* __restrict__ x, unsigned short* __restrict__ xb)
{
    int i = blockIdx.x * 256 + threadIdx.x;
    float4 v = reinterpret_cast<const float4*>(x)[i];
    int2 o;
    o.x = pack2(v.x, v.y);
    o.y = pack2(v.z, v.w);
    reinterpret_cast<int2*>(xb)[i] = o;
}

// ---------------- router: sigmoid + top-2 ----------------
__global__ __launch_bounds__(256) void router_kernel(
    const float* __restrict__ x, const float* __restrict__ gate,
    const float* __restrict__ bias, float* __restrict__ sc)
{
    const int n = blockIdx.x;
    const int t = threadIdx.x;
    float acc[8];
#pragma unroll
    for (int e = 0; e < 8; ++e) acc[e] = 0.f;
    const float* xr = x + (size_t)n * DIM;
    for (int d = t; d < DIM; d += 256) {
        float xv = xr[d];
        float4 g0 = *reinterpret_cast<const float4*>(gate + d * 8);
        float4 g1 = *reinterpret_cast<const float4*>(gate + d * 8 + 4);
        acc[0] += xv * g0.x; acc[1] += xv * g0.y;
        acc[2] += xv * g0.z; acc[3] += xv * g0.w;
        acc[4] += xv * g1.x; acc[5] += xv * g1.y;
        acc[6] += xv * g1.z; acc[7] += xv * g1.w;
    }
#pragma unroll
    for (int e = 0; e < 8; ++e) {
#pragma unroll
        for (int off = 32; off > 0; off >>= 1)
            acc[e] += __shfl_down(acc[e], off, 64);
    }
    __shared__ float red[4][8];
    const int lane = t & 63, wv = t >> 6;
    if (lane == 0) {
#pragma unroll
        for (int e = 0; e < 8; ++e) red[wv][e] = acc[e];
    }
    __syncthreads();
    if (t == 0) {
        float scv[8];
#pragma unroll
        for (int e = 0; e < 8; ++e) {
            float v = red[0][e] + red[1][e] + red[2][e] + red[3][e];
            scv[e] = 1.f / (1.f + expf(-v));
        }
        int i1 = 0; float b1 = -1e30f;
#pragma unroll
        for (int e = 0; e < 8; ++e) { float b = scv[e] + bias[e]; if (b > b1) { b1 = b; i1 = e; } }
        int i2 = -1; float b2 = -1e30f;
#pragma unroll
        for (int e = 0; e < 8; ++e) { if (e == i1) continue; float b = scv[e] + bias[e]; if (b > b2) { b2 = b; i2 = e; } }
#pragma unroll
        for (int e = 0; e < 8; ++e)
            sc[n * 8 + e] = (e == i1 || e == i2) ? scv[e] : 0.f;
    }
}

// ---------------- phase A: per-expert up-proj (g|u) + fused silu -> h2 ----------------
// grid: (token tiles 16, hidden tiles 16, 9 experts), block 256 (4 waves 2x2)
__global__ __launch_bounds__(256) void expert_gu_kernel(
    const unsigned short* __restrict__ xb,
    const float* __restrict__ w1, const float* __restrict__ w3,
    const float* __restrict__ sw1, const float* __restrict__ sw3,
    const float* __restrict__ s,
    unsigned short* __restrict__ h2)
{
    const int e  = blockIdx.z;
    const int m0 = blockIdx.x * 128;
    const int n0 = blockIdx.y * 64;
    const float* w1e = (e < NEXP) ? (w1 + (size_t)e * HID * DIM) : sw1;
    const float* w3e = (e < NEXP) ? (w3 + (size_t)e * HID * DIM) : sw3;

    __shared__ alignas(128) char lA[128 * 128];   // 128 tok x 64 bf16 (swizzled)
    __shared__ alignas(128) char lB1[64 * 128];   // 64 hid x 64 bf16
    __shared__ alignas(128) char lB2[64 * 128];

    const int t = threadIdx.x;
    const int lane = t & 63, wv = t >> 6;
    const int wm = wv >> 1, wn = wv & 1;
    const int lr = lane & 15, hi = lane >> 4;

    f32x4 accG[4][2], accU[4][2];
    const f32x4 zz = {0.f, 0.f, 0.f, 0.f};
#pragma unroll
    for (int m = 0; m < 4; ++m)
#pragma unroll
        for (int n = 0; n < 2; ++n) { accG[m][n] = zz; accU[m][n] = zz; }

    const int arow = t >> 1, ahalf = t & 1;   // A staging: 64B/thread
    const int brow = t >> 2, bq = t & 3;      // B staging: 32B/thread

    for (int k0 = 0; k0 < DIM; k0 += 64) {
        // stage A (x bf16)
        {
            const unsigned short* asrc = xb + (size_t)(m0 + arow) * DIM + k0 + ahalf * 32;
#pragma unroll
            for (int j = 0; j < 4; ++j) {
                int4 v = *reinterpret_cast<const int4*>(asrc + j * 8);
                int b = ahalf * 64 + j * 16;
                *reinterpret_cast<int4*>(lA + arow * 128 + (b ^ ((arow & 7) << 4))) = v;
            }
        }
        // stage B1/B2 (fp32 -> bf16 on the fly)
        {
            const float* p1 = w1e + (size_t)(n0 + brow) * DIM + k0 + bq * 16;
            const float* p3 = w3e + (size_t)(n0 + brow) * DIM + k0 + bq * 16;
            float4 v0 = *reinterpret_cast<const float4*>(p1);
            float4 v1 = *reinterpret_cast<const float4*>(p1 + 4);
            float4 v2 = *reinterpret_cast<const float4*>(p1 + 8);
            float4 v3 = *reinterpret_cast<const float4*>(p1 + 12);
            int4 c0 = make_int4(pack2(v0.x, v0.y), pack2(v0.z, v0.w), pack2(v1.x, v1.y), pack2(v1.z, v1.w));
            int4 c1 = make_int4(pack2(v2.x, v2.y), pack2(v2.z, v2.w), pack2(v3.x, v3.y), pack2(v3.z, v3.w));
            int sw = (brow & 7) << 4;
            int b = bq * 32;
            *reinterpret_cast<int4*>(lB1 + brow * 128 + (b ^ sw)) = c0;
            *reinterpret_cast<int4*>(lB1 + brow * 128 + ((b + 16) ^ sw)) = c1;
            v0 = *reinterpret_cast<const float4*>(p3);
            v1 = *reinterpret_cast<const float4*>(p3 + 4);
            v2 = *reinterpret_cast<const float4*>(p3 + 8);
            v3 = *reinterpret_cast<const float4*>(p3 + 12);
            c0 = make_int4(pack2(v0.x, v0.y), pack2(v0.z, v0.w), pack2(v1.x, v1.y), pack2(v1.z, v1.w));
            c1 = make_int4(pack2(v2.x, v2.y), pack2(v2.z, v2.w), pack2(v3.x, v3.y), pack2(v3.z, v3.w));
            *reinterpret_cast<int4*>(lB2 + brow * 128 + (b ^ sw)) = c0;
            *reinterpret_cast<int4*>(lB2 + brow * 128 + ((b + 16) ^ sw)) = c1;
        }
        __syncthreads();
#pragma unroll
        for (int kk = 0; kk < 2; ++kk) {
            bf16x8 af[4], b1f[2], b2f[2];
            const int cb = kk * 64 + hi * 16;
#pragma unroll
            for (int m = 0; m < 4; ++m) {
                int row = wm * 64 + m * 16 + lr;
                af[m] = *reinterpret_cast<const bf16x8*>(lA + row * 128 + (cb ^ ((row & 7) << 4)));
            }
#pragma unroll
            for (int n = 0; n < 2; ++n) {
                int row = wn * 32 + n * 16 + lr;
                int off = row * 128 + (cb ^ ((row & 7) << 4));
                b1f[n] = *reinterpret_cast<const bf16x8*>(lB1 + off);
                b2f[n] = *reinterpret_cast<const bf16x8*>(lB2 + off);
            }
#pragma unroll
            for (int m = 0; m < 4; ++m)
#pragma unroll
                for (int n = 0; n < 2; ++n) {
                    accG[m][n] = __builtin_amdgcn_mfma_f32_16x16x32_bf16(af[m], b1f[n], accG[m][n], 0, 0, 0);
                    accU[m][n] = __builtin_amdgcn_mfma_f32_16x16x32_bf16(af[m], b2f[n], accU[m][n], 0, 0, 0);
                }
        }
        __syncthreads();
    }

    // epilogue: h = silu(s*g) * (s*u), store bf16
#pragma unroll
    for (int m = 0; m < 4; ++m) {
#pragma unroll
        for (int r = 0; r < 4; ++r) {
            int tok = m0 + wm * 64 + m * 16 + hi * 4 + r;
            float sv = (e < NEXP) ? s[tok * NEXP + e] : 1.0f;
#pragma unroll
            for (int n = 0; n < 2; ++n) {
                int col = n0 + wn * 32 + n * 16 + lr;
                float g = bf2f(f2bf(accG[m][n][r] * sv));
                float u = bf2f(f2bf(accU[m][n][r] * sv));
                float hval = (g / (1.f + __expf(-g))) * u;
                h2[(size_t)tok * KP + e * HID + col] = (unsigned short)f2bf(hval);
            }
        }
    }
}

// ---------------- phase B: down-proj, K=9216 over (e,k) ----------------
// grid: (token tiles 16, dim tiles 16), block 256 (4 waves 2x2)
__global__ __launch_bounds__(256) void down_kernel(
    const unsigned short* __restrict__ h2,
    const float* __restrict__ w2, const float* __restrict__ sw2,
    float* __restrict__ out)
{
    const int m0 = blockIdx.x * 128;
    const int n0 = blockIdx.y * 128;
    __shared__ alignas(128) char lA[128 * 128];
    __shared__ alignas(128) char lB[128 * 128];
    const int t = threadIdx.x;
    const int lane = t & 63, wv = t >> 6;
    const int wm = wv >> 1, wn = wv & 1;
    const int lr = lane & 15, hi = lane >> 4;
    f32x4 acc[4][4];
    const f32x4 zz = {0.f, 0.f, 0.f, 0.f};
#pragma unroll
    for (int m = 0; m < 4; ++m)
#pragma unroll
        for (int n = 0; n < 4; ++n) acc[m][n] = zz;

    const int arow = t >> 1, ahalf = t & 1;

    for (int k0 = 0; k0 < KP; k0 += 64) {
        const int e = k0 >> 10, kin = k0 & 1023;
        // stage A (h2 bf16)
        {
            const unsigned short* asrc = h2 + (size_t)(m0 + arow) * KP + k0 + ahalf * 32;
#pragma unroll
            for (int j = 0; j < 4; ++j) {
                int4 v = *reinterpret_cast<const int4*>(asrc + j * 8);
                int b = ahalf * 64 + j * 16;
                *reinterpret_cast<int4*>(lA + arow * 128 + (b ^ ((arow & 7) << 4))) = v;
            }
        }
        // stage B (w2 fp32 -> bf16)
        {
            const float* bsrc = (e < NEXP)
                ? (w2 + ((size_t)e * DIM + (n0 + arow)) * HID + kin + ahalf * 32)
                : (sw2 + (size_t)(n0 + arow) * HID + kin + ahalf * 32);
#pragma unroll
            for (int j = 0; j < 4; ++j) {
                float4 v0 = *reinterpret_cast<const float4*>(bsrc + j * 8);
                float4 v1 = *reinterpret_cast<const float4*>(bsrc + j * 8 + 4);
                int4 c = make_int4(pack2(v0.x, v0.y), pack2(v0.z, v0.w), pack2(v1.x, v1.y), pack2(v1.z, v1.w));
                int b = ahalf * 64 + j * 16;
                *reinterpret_cast<int4*>(lB + arow * 128 + (b ^ ((arow & 7) << 4))) = c;
            }
        }
        __syncthreads();
#pragma unroll
        for (int kk = 0; kk < 2; ++kk) {
            bf16x8 af[4], bfr[4];
            const int cb = kk * 64 + hi * 16;
#pragma unroll
            for (int m = 0; m < 4; ++m) {
                int row = wm * 64 + m * 16 + lr;
                af[m] = *reinterpret_cast<const bf16x8*>(lA + row * 128 + (cb ^ ((row & 7) << 4)));
                int rowb = wn * 64 + m * 16 + lr;
                bfr[m] = *reinterpret_cast<const bf16x8*>(lB + rowb * 128 + (cb ^ ((rowb & 7) << 4)));
            }
#pragma unroll
            for (int m = 0; m < 4; ++m)
#pragma unroll
                for (int n = 0; n < 4; ++n)
                    acc[m][n] = __builtin_amdgcn_mfma_f32_16x16x32_bf16(af[m], bfr[n], acc[m][n], 0, 0, 0);
        }
        __syncthreads();
    }

#pragma unroll
    for (int m = 0; m < 4; ++m)
#pragma unroll
        for (int r = 0; r < 4; ++r) {
            int tok = m0 + wm * 64 + m * 16 + hi * 4 + r;
            float* orow = out + (size_t)tok * DIM + n0 + wn * 64;
#pragma unroll
            for (int n = 0; n < 4; ++n)
                orow[n * 16 + lr] = acc[m][n][r];
        }
}

extern "C" void kernel_launch(void* const* d_in, const int* in_sizes, int n_in,
                              void* d_out, int out_size, void* d_ws, size_t ws_size,
                              hipStream_t stream) {
    const float* x    = (const float*)d_in[0];
    const float* gate = (const float*)d_in[1];
    const float* bias = (const float*)d_in[2];
    const float* w1   = (const float*)d_in[3];
    const float* w2   = (const float*)d_in[4];
    const float* w3   = (const float*)d_in[5];
    const float* sw1  = (const float*)d_in[6];
    const float* sw2  = (const float*)d_in[7];
    const float* sw3  = (const float*)d_in[8];
    float* out = (float*)d_out;

    char* ws = (char*)d_ws;
    unsigned short* xb = (unsigned short*)(ws);            // 8 MB
    float* sc          = (float*)(ws + 8388608);           // 64 KB
    unsigned short* h2 = (unsigned short*)(ws + 8454144);  // 36 MB: [2048][9216] bf16

    cast_x_kernel<<<dim3(NTOK * DIM / 4 / 256), 256, 0, stream>>>(x, xb);
    router_kernel<<<dim3(NTOK), 256, 0, stream>>>(x, gate, bias, sc);
    expert_gu_kernel<<<dim3(16, 16, NE), 256, 0, stream>>>(xb, w1, w3, sw1, sw3, sc, h2);
    down_kernel<<<dim3(16, 16), 256, 0, stream>>>(h2, w2, sw2, out);
}

// Round 2
// 601.373 us; speedup vs baseline: 1.4129x; 1.4129x over previous
//
#include <hip/hip_runtime.h>

#define NTOK 2048
#define DIM  2048
#define HID  1024
#define NEXP 8
#define SHBASE 5120   // padded routed slots <= 5120; shared tokens at 5120..7167

typedef float f32x4 __attribute__((ext_vector_type(4)));
typedef __bf16 bf16x8 __attribute__((ext_vector_type(8)));

__device__ __forceinline__ unsigned int f2bf(float f) {
    unsigned int u = __float_as_uint(f);
    u += 0x7FFFu + ((u >> 16) & 1u);   // RNE
    return u >> 16;
}
__device__ __forceinline__ float bf2f(unsigned int h) {
    return __uint_as_float(h << 16);
}
__device__ __forceinline__ int pack2(float a, float b) {
    return (int)(f2bf(a) | (f2bf(b) << 16));
}
__device__ __forceinline__ void gload16(const void* g, void* l) {
    __builtin_amdgcn_global_load_lds(
        (__attribute__((address_space(1))) void*)(g),
        (__attribute__((address_space(3))) void*)(l), 16, 0, 0);
}

// ---------------- generic fp32 -> bf16 cast ----------------
__global__ __launch_bounds__(256) void cast_kernel(
    const float* __restrict__ src, unsigned short* __restrict__ dst, int n4)
{
    int i = blockIdx.x * 256 + threadIdx.x;
    if (i >= n4) return;
    float4 v = reinterpret_cast<const float4*>(src)[i];
    int2 o;
    o.x = pack2(v.x, v.y);
    o.y = pack2(v.z, v.w);
    reinterpret_cast<int2*>(dst)[i] = o;
}

// ---------------- router: sigmoid + top-2 ----------------
__global__ __launch_bounds__(256) void router_kernel(
    const float* __restrict__ x, const float* __restrict__ gate,
    const float* __restrict__ bias, float* __restrict__ sc, int* __restrict__ top2)
{
    const int n = blockIdx.x;
    const int t = threadIdx.x;
    float acc[8];
#pragma unroll
    for (int e = 0; e < 8; ++e) acc[e] = 0.f;
    const float* xr = x + (size_t)n * DIM;
    for (int d = t; d < DIM; d += 256) {
        float xv = xr[d];
        float4 g0 = *reinterpret_cast<const float4*>(gate + d * 8);
        float4 g1 = *reinterpret_cast<const float4*>(gate + d * 8 + 4);
        acc[0] += xv * g0.x; acc[1] += xv * g0.y;
        acc[2] += xv * g0.z; acc[3] += xv * g0.w;
        acc[4] += xv * g1.x; acc[5] += xv * g1.y;
        acc[6] += xv * g1.z; acc[7] += xv * g1.w;
    }
#pragma unroll
    for (int e = 0; e < 8; ++e) {
#pragma unroll
        for (int off = 32; off > 0; off >>= 1)
            acc[e] += __shfl_down(acc[e], off, 64);
    }
    __shared__ float red[4][8];
    const int lane = t & 63, wv = t >> 6;
    if (lane == 0) {
#pragma unroll
        for (int e = 0; e < 8; ++e) red[wv][e] = acc[e];
    }
    __syncthreads();
    if (t == 0) {
        float scv[8];
#pragma unroll
        for (int e = 0; e < 8; ++e) {
            float v = red[0][e] + red[1][e] + red[2][e] + red[3][e];
            scv[e] = 1.f / (1.f + expf(-v));
        }
        int i1 = 0; float b1 = -1e30f;
#pragma unroll
        for (int e = 0; e < 8; ++e) { float b = scv[e] + bias[e]; if (b > b1) { b1 = b; i1 = e; } }
        int i2 = -1; float b2 = -1e30f;
#pragma unroll
        for (int e = 0; e < 8; ++e) { if (e == i1) continue; float b = scv[e] + bias[e]; if (b > b2) { b2 = b; i2 = e; } }
#pragma unroll
        for (int e = 0; e < 8; ++e) sc[n * 8 + e] = scv[e];
        top2[n * 2]     = i1;
        top2[n * 2 + 1] = i2;
    }
}

// ---------------- per-expert token lists (padded bases) ----------------
__global__ __launch_bounds__(256) void lists_kernel(
    const int* __restrict__ top2, int* __restrict__ gcnt, int* __restrict__ gbase,
    int* __restrict__ tid, int* __restrict__ rows)
{
    __shared__ int cnt[8], run[8], base[8];
    const int t = threadIdx.x;
    if (t < 8) { cnt[t] = 0; run[t] = 0; }
    __syncthreads();
    for (int tok = t; tok < NTOK; tok += 256) {
        atomicAdd(&cnt[top2[tok * 2]], 1);
        atomicAdd(&cnt[top2[tok * 2 + 1]], 1);
    }
    __syncthreads();
    if (t == 0) {
        int c = 0;
        for (int e = 0; e < 8; ++e) { base[e] = c; c += (cnt[e] + 127) & ~127; }
    }
    __syncthreads();
    for (int tok = t; tok < NTOK; tok += 256) {
#pragma unroll
        for (int k = 0; k < 2; ++k) {
            int e = top2[tok * 2 + k];
            int pos = atomicAdd(&run[e], 1);
            tid[e * NTOK + pos] = tok;
            rows[tok * 2 + k] = base[e] + pos;
        }
    }
    __syncthreads();
    if (t < 8) { gcnt[t] = cnt[t]; gbase[t] = base[t]; }
}

// ---------------- up-proj: gathered tokens, fused silu -> h2g ----------------
// grid (16, HID/64, 9), block 256 (4 waves 2x2), early-exit on inactive tiles
__global__ __launch_bounds__(256) void up_kernel(
    const unsigned short* __restrict__ xb,
    const unsigned short* __restrict__ w1b, const unsigned short* __restrict__ w3b,
    const unsigned short* __restrict__ sw1b, const unsigned short* __restrict__ sw3b,
    const float* __restrict__ sc, const int* __restrict__ gcnt, const int* __restrict__ gbase,
    const int* __restrict__ tid, unsigned short* __restrict__ h2g)
{
    const int e = blockIdx.z;
    int cnt, base;
    const unsigned short *w1e, *w3e;
    const int* tl = nullptr;
    if (e < NEXP) {
        cnt = gcnt[e];
        if ((int)blockIdx.x * 128 >= cnt) return;
        base = gbase[e];
        w1e = w1b + (size_t)e * HID * DIM;
        w3e = w3b + (size_t)e * HID * DIM;
        tl = tid + e * NTOK;
    } else {
        cnt = NTOK; base = SHBASE; w1e = sw1b; w3e = sw3b;
    }
    const int m0 = blockIdx.x * 128, n0 = blockIdx.y * 64;

    __shared__ char lA[16384];   // 128 tok rows x 128B (linear; source pre-swizzled)
    __shared__ char lB1[8192];   // 64 hid rows x 128B
    __shared__ char lB2[8192];

    const int t = threadIdx.x;
    const int lane = t & 63, wv = t >> 6;
    const int wm = wv >> 1, wn = wv & 1;
    const int lr = lane & 15, hi = lane >> 4;
    const int srow = lane >> 3;            // 0..7 within wave pass
    const int scolb = (lane & 7) << 4;     // byte within 128B row chunk

    // staging source pointers (per-lane, swizzle folded into global address)
    const char* aS[4]; char* aD[4];
#pragma unroll
    for (int p = 0; p < 4; ++p) {
        int r = p * 32 + wv * 8 + srow;
        int ridx = (e < NEXP) ? tl[min(m0 + r, cnt - 1)] : (m0 + r);
        aS[p] = (const char*)xb + (size_t)ridx * (DIM * 2) + (scolb ^ ((r & 7) << 4));
        aD[p] = lA + p * 4096 + wv * 1024;
    }
    const char *b1S[2], *b3S[2]; char *bD[2];
#pragma unroll
    for (int q = 0; q < 2; ++q) {
        int r = q * 32 + wv * 8 + srow;
        size_t ro = (size_t)(n0 + r) * (DIM * 2) + (scolb ^ ((r & 7) << 4));
        b1S[q] = (const char*)w1e + ro;
        b3S[q] = (const char*)w3e + ro;
        bD[q] = (char*)0 + q * 4096 + wv * 1024;   // offset only
    }

    f32x4 accG[4][2], accU[4][2];
    const f32x4 zz = {0.f, 0.f, 0.f, 0.f};
#pragma unroll
    for (int m = 0; m < 4; ++m)
#pragma unroll
        for (int n = 0; n < 2; ++n) { accG[m][n] = zz; accU[m][n] = zz; }

    for (int kb = 0; kb < DIM * 2; kb += 128) {
#pragma unroll
        for (int p = 0; p < 4; ++p) gload16(aS[p] + kb, aD[p]);
#pragma unroll
        for (int q = 0; q < 2; ++q) {
            size_t off = q * 4096 + wv * 1024;
            gload16(b1S[q] + kb, lB1 + off);
            gload16(b3S[q] + kb, lB2 + off);
        }
        __syncthreads();
#pragma unroll
        for (int kk = 0; kk < 2; ++kk) {
            bf16x8 af[4], b1f[2], b2f[2];
            const int cb = kk * 64 + hi * 16;
#pragma unroll
            for (int m = 0; m < 4; ++m) {
                int row = wm * 64 + m * 16 + lr;
                af[m] = *reinterpret_cast<const bf16x8*>(lA + row * 128 + (cb ^ ((row & 7) << 4)));
            }
#pragma unroll
            for (int n = 0; n < 2; ++n) {
                int row = wn * 32 + n * 16 + lr;
                int off = row * 128 + (cb ^ ((row & 7) << 4));
                b1f[n] = *reinterpret_cast<const bf16x8*>(lB1 + off);
                b2f[n] = *reinterpret_cast<const bf16x8*>(lB2 + off);
            }
#pragma unroll
            for (int m = 0; m < 4; ++m)
#pragma unroll
                for (int n = 0; n < 2; ++n) {
                    accG[m][n] = __builtin_amdgcn_mfma_f32_16x16x32_bf16(af[m], b1f[n], accG[m][n], 0, 0, 0);
                    accU[m][n] = __builtin_amdgcn_mfma_f32_16x16x32_bf16(af[m], b2f[n], accU[m][n], 0, 0, 0);
                }
        }
        __syncthreads();
    }

    // epilogue: h = silu(s*g) * (s*u) with bf16 rounding to match reference
#pragma unroll
    for (int m = 0; m < 4; ++m) {
#pragma unroll
        for (int r = 0; r < 4; ++r) {
            int row = wm * 64 + m * 16 + hi * 4 + r;
            float sv = 1.0f;
            if (e < NEXP) {
                int tok = tl[min(m0 + row, cnt - 1)];
                sv = sc[tok * NEXP + e];
            }
            unsigned short* hrow = h2g + (size_t)(base + m0 + row) * HID + n0;
#pragma unroll
            for (int n = 0; n < 2; ++n) {
                int col = wn * 32 + n * 16 + lr;
                float g = bf2f(f2bf(accG[m][n][r] * sv));
                float u = bf2f(f2bf(accU[m][n][r] * sv));
                float hval = (g / (1.f + __expf(-g))) * u;
                hrow[col] = (unsigned short)f2bf(hval);
            }
        }
    }
}

// ---------------- down-proj per expert; routed -> rb (bf16), shared -> out (fp32) ----------------
// grid (16, DIM/128, 9), block 256
__global__ __launch_bounds__(256) void down_kernel(
    const unsigned short* __restrict__ h2g,
    const unsigned short* __restrict__ w2b, const unsigned short* __restrict__ sw2b,
    const int* __restrict__ gcnt, const int* __restrict__ gbase,
    unsigned short* __restrict__ rb, float* __restrict__ out)
{
    const int e = blockIdx.z;
    int cnt, base;
    const unsigned short* w2e;
    if (e < NEXP) {
        cnt = gcnt[e];
        if ((int)blockIdx.x * 128 >= cnt) return;
        base = gbase[e];
        w2e = w2b + (size_t)e * DIM * HID;
    } else {
        cnt = NTOK; base = SHBASE; w2e = sw2b;
    }
    const int m0 = blockIdx.x * 128, n0 = blockIdx.y * 128;

    __shared__ char lA[16384];
    __shared__ char lB[16384];

    const int t = threadIdx.x;
    const int lane = t & 63, wv = t >> 6;
    const int wm = wv >> 1, wn = wv & 1;
    const int lr = lane & 15, hi = lane >> 4;
    const int srow = lane >> 3;
    const int scolb = (lane & 7) << 4;

    const char* aS[4]; const char* bS[4];
#pragma unroll
    for (int p = 0; p < 4; ++p) {
        int r = p * 32 + wv * 8 + srow;
        aS[p] = (const char*)h2g + (size_t)(base + m0 + r) * (HID * 2) + (scolb ^ ((r & 7) << 4));
        bS[p] = (const char*)w2e + (size_t)(n0 + r) * (HID * 2) + (scolb ^ ((r & 7) << 4));
    }

    f32x4 acc[4][4];
    const f32x4 zz = {0.f, 0.f, 0.f, 0.f};
#pragma unroll
    for (int m = 0; m < 4; ++m)
#pragma unroll
        for (int n = 0; n < 4; ++n) acc[m][n] = zz;

    for (int kb = 0; kb < HID * 2; kb += 128) {
#pragma unroll
        for (int p = 0; p < 4; ++p) {
            size_t off = p * 4096 + wv * 1024;
            gload16(aS[p] + kb, lA + off);
            gload16(bS[p] + kb, lB + off);
        }
        __syncthreads();
#pragma unroll
        for (int kk = 0; kk < 2; ++kk) {
            bf16x8 af[4], bfr[4];
            const int cb = kk * 64 + hi * 16;
#pragma unroll
            for (int m = 0; m < 4; ++m) {
                int row = wm * 64 + m * 16 + lr;
                af[m] = *reinterpret_cast<const bf16x8*>(lA + row * 128 + (cb ^ ((row & 7) << 4)));
                int rowb = wn * 64 + m * 16 + lr;
                bfr[m] = *reinterpret_cast<const bf16x8*>(lB + rowb * 128 + (cb ^ ((rowb & 7) << 4)));
            }
#pragma unroll
            for (int m = 0; m < 4; ++m)
#pragma unroll
                for (int n = 0; n < 4; ++n)
                    acc[m][n] = __builtin_amdgcn_mfma_f32_16x16x32_bf16(af[m], bfr[n], acc[m][n], 0, 0, 0);
        }
        __syncthreads();
    }

#pragma unroll
    for (int m = 0; m < 4; ++m)
#pragma unroll
        for (int r = 0; r < 4; ++r) {
            int row = wm * 64 + m * 16 + hi * 4 + r;
            if (e < NEXP) {
                unsigned short* rrow = rb + (size_t)(base + m0 + row) * DIM + n0 + wn * 64;
#pragma unroll
                for (int n = 0; n < 4; ++n)
                    rrow[n * 16 + lr] = (unsigned short)f2bf(acc[m][n][r]);
            } else {
                float* orow = out + (size_t)(m0 + row) * DIM + n0 + wn * 64;
#pragma unroll
                for (int n = 0; n < 4; ++n)
                    orow[n * 16 + lr] = acc[m][n][r];
            }
        }
}

// ---------------- combine: out(tok) += rb(row1) + rb(row2) ----------------
__global__ __launch_bounds__(256) void combine_kernel(
    const int* __restrict__ rows, const unsigned short* __restrict__ rb,
    float* __restrict__ out)
{
    int i = blockIdx.x * 256 + threadIdx.x;   // 2048*256 threads, 8 floats each
    int tok = i >> 8, g = i & 255;
    int r1 = rows[tok * 2], r2 = rows[tok * 2 + 1];
    float4* op = reinterpret_cast<float4*>(out + (size_t)tok * DIM + g * 8);
    int4 a = *reinterpret_cast<const int4*>(rb + (size_t)r1 * DIM + g * 8);
    int4 b = *reinterpret_cast<const int4*>(rb + (size_t)r2 * DIM + g * 8);
    float4 o0 = op[0], o1 = op[1];
    o0.x += bf2f((unsigned)a.x & 0xFFFF) + bf2f((unsigned)b.x & 0xFFFF);
    o0.y += bf2f((unsigned)a.x >> 16)    + bf2f((unsigned)b.x >> 16);
    o0.z += bf2f((unsigned)a.y & 0xFFFF) + bf2f((unsigned)b.y & 0xFFFF);
    o0.w += bf2f((unsigned)a.y >> 16)    + bf2f((unsigned)b.y >> 16);
    o1.x += bf2f((unsigned)a.z & 0xFFFF) + bf2f((unsigned)b.z & 0xFFFF);
    o1.y += bf2f((unsigned)a.z >> 16)    + bf2f((unsigned)b.z >> 16);
    o1.z += bf2f((unsigned)a.w & 0xFFFF) + bf2f((unsigned)b.w & 0xFFFF);
    o1.w += bf2f((unsigned)a.w >> 16)    + bf2f((unsigned)b.w >> 16);
    op[0] = o0; op[1] = o1;
}

extern "C" void kernel_launch(void* const* d_in, const int* in_sizes, int n_in,
                              void* d_out, int out_size, void* d_ws, size_t ws_size,
                              hipStream_t stream) {
    const float* x    = (const float*)d_in[0];
    const float* gate = (const float*)d_in[1];
    const float* bias = (const float*)d_in[2];
    const float* w1   = (const float*)d_in[3];
    const float* w2   = (const float*)d_in[4];
    const float* w3   = (const float*)d_in[5];
    const float* sw1  = (const float*)d_in[6];
    const float* sw2  = (const float*)d_in[7];
    const float* sw3  = (const float*)d_in[8];
    float* out = (float*)d_out;

    char* ws = (char*)d_ws;
    size_t o = 0;
    unsigned short* xb   = (unsigned short*)(ws + o); o += 8388608;    // 2048x2048 bf16
    unsigned short* w1b  = (unsigned short*)(ws + o); o += 33554432;   // 8x1024x2048 bf16
    unsigned short* w3b  = (unsigned short*)(ws + o); o += 33554432;
    unsigned short* w2b  = (unsigned short*)(ws + o); o += 33554432;   // 8x2048x1024 bf16
    unsigned short* sw1b = (unsigned short*)(ws + o); o += 4194304;
    unsigned short* sw3b = (unsigned short*)(ws + o); o += 4194304;
    unsigned short* sw2b = (unsigned short*)(ws + o); o += 4194304;
    unsigned short* h2g  = (unsigned short*)(ws + o); o += 14680064;   // 7168x1024 bf16
    unsigned short* rb   = (unsigned short*)(ws + o); o += 20971520;   // 5120x2048 bf16
    float* sc            = (float*)(ws + o);          o += 65536;
    int* top2            = (int*)(ws + o);            o += 16384;
    int* tid             = (int*)(ws + o);            o += 65536;
    int* rows            = (int*)(ws + o);            o += 16384;
    int* gcnt            = (int*)(ws + o);            o += 256;
    int* gbase           = (int*)(ws + o);            o += 256;

    cast_kernel<<<4096,  256, 0, stream>>>(x,   xb,   1048576);
    cast_kernel<<<16384, 256, 0, stream>>>(w1,  w1b,  4194304);
    cast_kernel<<<16384, 256, 0, stream>>>(w3,  w3b,  4194304);
    cast_kernel<<<16384, 256, 0, stream>>>(w2,  w2b,  4194304);
    cast_kernel<<<2048,  256, 0, stream>>>(sw1, sw1b, 524288);
    cast_kernel<<<2048,  256, 0, stream>>>(sw3, sw3b, 524288);
    cast_kernel<<<2048,  256, 0, stream>>>(sw2, sw2b, 524288);
    router_kernel<<<2048, 256, 0, stream>>>(x, gate, bias, sc, top2);
    lists_kernel<<<1, 256, 0, stream>>>(top2, gcnt, gbase, tid, rows);
    up_kernel<<<dim3(16, 16, 9), 256, 0, stream>>>(xb, w1b, w3b, sw1b, sw3b, sc, gcnt, gbase, tid, h2g);
    down_kernel<<<dim3(16, 16, 9), 256, 0, stream>>>(h2g, w2b, sw2b, gcnt, gbase, rb, out);
    combine_kernel<<<2048, 256, 0, stream>>>(rows, rb, out);
}

// Round 3
// 535.420 us; speedup vs baseline: 1.5869x; 1.1232x over previous
//
#include <hip/hip_runtime.h>

#define NTOK 2048
#define DIM  2048
#define HID  1024
#define NEXP 8
#define SHBASE 6144   // routed slots padded to 256 <= 6144; shared rows 6144..8191

typedef float f32x4 __attribute__((ext_vector_type(4)));
typedef __bf16 bf16x8 __attribute__((ext_vector_type(8)));

__device__ __forceinline__ unsigned int f2bf(float f) {
    unsigned int u = __float_as_uint(f);
    u += 0x7FFFu + ((u >> 16) & 1u);   // RNE
    return u >> 16;
}
__device__ __forceinline__ float bf2f(unsigned int h) {
    return __uint_as_float(h << 16);
}
__device__ __forceinline__ int pack2(float a, float b) {
    return (int)(f2bf(a) | (f2bf(b) << 16));
}
__device__ __forceinline__ void gload16(const void* g, void* l) {
    __builtin_amdgcn_global_load_lds(
        (__attribute__((address_space(1))) void*)(g),
        (__attribute__((address_space(3))) void*)(l), 16, 0, 0);
}
#define MFMA __builtin_amdgcn_mfma_f32_16x16x32_bf16

// ---------------- generic fp32 -> bf16 cast ----------------
__global__ __launch_bounds__(256) void cast_kernel(
    const float* __restrict__ src, unsigned short* __restrict__ dst, int n4)
{
    int i = blockIdx.x * 256 + threadIdx.x;
    if (i >= n4) return;
    float4 v = reinterpret_cast<const float4*>(src)[i];
    int2 o;
    o.x = pack2(v.x, v.y);
    o.y = pack2(v.z, v.w);
    reinterpret_cast<int2*>(dst)[i] = o;
}

// ---------------- router: sigmoid + top-2 ----------------
__global__ __launch_bounds__(256) void router_kernel(
    const float* __restrict__ x, const float* __restrict__ gate,
    const float* __restrict__ bias, float* __restrict__ sc, int* __restrict__ top2)
{
    const int n = blockIdx.x;
    const int t = threadIdx.x;
    float acc[8];
#pragma unroll
    for (int e = 0; e < 8; ++e) acc[e] = 0.f;
    const float* xr = x + (size_t)n * DIM;
    for (int d = t; d < DIM; d += 256) {
        float xv = xr[d];
        float4 g0 = *reinterpret_cast<const float4*>(gate + d * 8);
        float4 g1 = *reinterpret_cast<const float4*>(gate + d * 8 + 4);
        acc[0] += xv * g0.x; acc[1] += xv * g0.y;
        acc[2] += xv * g0.z; acc[3] += xv * g0.w;
        acc[4] += xv * g1.x; acc[5] += xv * g1.y;
        acc[6] += xv * g1.z; acc[7] += xv * g1.w;
    }
#pragma unroll
    for (int e = 0; e < 8; ++e) {
#pragma unroll
        for (int off = 32; off > 0; off >>= 1)
            acc[e] += __shfl_down(acc[e], off, 64);
    }
    __shared__ float red[4][8];
    const int lane = t & 63, wv = t >> 6;
    if (lane == 0) {
#pragma unroll
        for (int e = 0; e < 8; ++e) red[wv][e] = acc[e];
    }
    __syncthreads();
    if (t == 0) {
        float scv[8];
#pragma unroll
        for (int e = 0; e < 8; ++e) {
            float v = red[0][e] + red[1][e] + red[2][e] + red[3][e];
            scv[e] = 1.f / (1.f + expf(-v));
        }
        int i1 = 0; float b1 = -1e30f;
#pragma unroll
        for (int e = 0; e < 8; ++e) { float b = scv[e] + bias[e]; if (b > b1) { b1 = b; i1 = e; } }
        int i2 = -1; float b2 = -1e30f;
#pragma unroll
        for (int e = 0; e < 8; ++e) { if (e == i1) continue; float b = scv[e] + bias[e]; if (b > b2) { b2 = b; i2 = e; } }
#pragma unroll
        for (int e = 0; e < 8; ++e) sc[n * 8 + e] = scv[e];
        top2[n * 2]     = i1;
        top2[n * 2 + 1] = i2;
    }
}

// ---------------- per-expert token lists (bases padded to 256) ----------------
__global__ __launch_bounds__(256) void lists_kernel(
    const int* __restrict__ top2, int* __restrict__ gcnt, int* __restrict__ gbase,
    int* __restrict__ tid, int* __restrict__ rows)
{
    __shared__ int cnt[8], run[8], base[8];
    const int t = threadIdx.x;
    if (t < 8) { cnt[t] = 0; run[t] = 0; }
    __syncthreads();
    for (int tok = t; tok < NTOK; tok += 256) {
        atomicAdd(&cnt[top2[tok * 2]], 1);
        atomicAdd(&cnt[top2[tok * 2 + 1]], 1);
    }
    __syncthreads();
    if (t == 0) {
        int c = 0;
        for (int e = 0; e < 8; ++e) { base[e] = c; c += (cnt[e] + 255) & ~255; }
    }
    __syncthreads();
    for (int tok = t; tok < NTOK; tok += 256) {
#pragma unroll
        for (int k = 0; k < 2; ++k) {
            int e = top2[tok * 2 + k];
            int pos = atomicAdd(&run[e], 1);
            tid[e * NTOK + pos] = tok;
            rows[tok * 2 + k] = base[e] + pos;
        }
    }
    __syncthreads();
    if (t < 8) { gcnt[t] = cnt[t]; gbase[t] = base[t]; }
}

// ---------------- up-proj: 256x128 tile (G and U), 8 waves, 2-phase dbuf ----------------
// grid (8, HID/128=8, 9), block 512
__global__ __launch_bounds__(512) void up_kernel(
    const unsigned short* __restrict__ xb,
    const unsigned short* __restrict__ w1b, const unsigned short* __restrict__ w3b,
    const unsigned short* __restrict__ sw1b, const unsigned short* __restrict__ sw3b,
    const float* __restrict__ sc, const int* __restrict__ gcnt, const int* __restrict__ gbase,
    const int* __restrict__ tid, unsigned short* __restrict__ h2g)
{
    const int e = blockIdx.z;
    int cnt, base;
    const unsigned short *w1e, *w3e;
    const int* tl = nullptr;
    if (e < NEXP) {
        cnt = gcnt[e];
        if ((int)blockIdx.x * 256 >= cnt) return;
        base = gbase[e];
        w1e = w1b + (size_t)e * HID * DIM;
        w3e = w3b + (size_t)e * HID * DIM;
        tl = tid + e * NTOK;
    } else {
        cnt = NTOK; base = SHBASE; w1e = sw1b; w3e = sw3b;
    }
    const int m0 = blockIdx.x * 256, n0 = blockIdx.y * 128;

    __shared__ char lds[131072];   // dbuf: [A 32K | B1 16K | B2 16K] x2

    const int t = threadIdx.x;
    const int lane = t & 63, wv = t >> 6;
    const int wm = wv >> 1, wn = wv & 1;      // 4x2 wave grid
    const int lr = lane & 15, hi = lane >> 4;

    // per-lane staging sources (swizzle folded into global address; LDS stays linear)
    const int scol = ((t & 7) << 4);
    const char* aS[4];
#pragma unroll
    for (int p = 0; p < 4; ++p) {
        int r = p * 64 + (t >> 3);
        int ridx = (e < NEXP) ? tl[min(m0 + r, cnt - 1)] : (m0 + r);
        aS[p] = (const char*)xb + (size_t)ridx * (DIM * 2) + (scol ^ ((r & 7) << 4));
    }
    const char *b1S[2], *b3S[2];
#pragma unroll
    for (int p = 0; p < 2; ++p) {
        int r = p * 64 + (t >> 3);
        size_t ro = (size_t)(n0 + r) * (DIM * 2) + (scol ^ ((r & 7) << 4));
        b1S[p] = (const char*)w1e + ro;
        b3S[p] = (const char*)w3e + ro;
    }

    f32x4 accG[4][4], accU[4][4];
    const f32x4 zz = {0.f, 0.f, 0.f, 0.f};
#pragma unroll
    for (int m = 0; m < 4; ++m)
#pragma unroll
        for (int n = 0; n < 4; ++n) { accG[m][n] = zz; accU[m][n] = zz; }

    auto STAGE = [&](int bo, int kb) {
#pragma unroll
        for (int p = 0; p < 4; ++p)
            gload16(aS[p] + kb, lds + bo + p * 8192 + wv * 1024);
#pragma unroll
        for (int p = 0; p < 2; ++p) {
            gload16(b1S[p] + kb, lds + bo + 32768 + p * 8192 + wv * 1024);
            gload16(b3S[p] + kb, lds + bo + 49152 + p * 8192 + wv * 1024);
        }
    };

    int bo = 0;
    STAGE(0, 0);
    __syncthreads();
    for (int it = 0; it < 32; ++it) {
        if (it < 31) STAGE(bo ^ 65536, (it + 1) * 128);
        const char* A  = lds + bo;
        const char* B1 = A + 32768;
        const char* B2 = A + 49152;
#pragma unroll
        for (int kk = 0; kk < 2; ++kk) {
            bf16x8 af[4], b1f[4], b2f[4];
            const int cb = kk * 64 + hi * 16;
#pragma unroll
            for (int m = 0; m < 4; ++m) {
                int row = wm * 64 + m * 16 + lr;
                af[m] = *reinterpret_cast<const bf16x8*>(A + row * 128 + (cb ^ ((row & 7) << 4)));
            }
#pragma unroll
            for (int n = 0; n < 4; ++n) {
                int row = wn * 64 + n * 16 + lr;
                int off = row * 128 + (cb ^ ((row & 7) << 4));
                b1f[n] = *reinterpret_cast<const bf16x8*>(B1 + off);
                b2f[n] = *reinterpret_cast<const bf16x8*>(B2 + off);
            }
#pragma unroll
            for (int m = 0; m < 4; ++m)
#pragma unroll
                for (int n = 0; n < 4; ++n) {
                    accG[m][n] = MFMA(af[m], b1f[n], accG[m][n], 0, 0, 0);
                    accU[m][n] = MFMA(af[m], b2f[n], accU[m][n], 0, 0, 0);
                }
        }
        __syncthreads();
        bo ^= 65536;
    }

    // epilogue: h = silu(s*g) * (s*u), bf16 rounding matches reference
#pragma unroll
    for (int m = 0; m < 4; ++m) {
#pragma unroll
        for (int r = 0; r < 4; ++r) {
            int row = wm * 64 + m * 16 + hi * 4 + r;
            float sv = 1.0f;
            if (e < NEXP) sv = sc[tl[min(m0 + row, cnt - 1)] * NEXP + e];
            unsigned short* hrow = h2g + (size_t)(base + m0 + row) * HID + n0;
#pragma unroll
            for (int n = 0; n < 4; ++n) {
                int col = wn * 64 + n * 16 + lr;
                float g = bf2f(f2bf(accG[m][n][r] * sv));
                float u = bf2f(f2bf(accU[m][n][r] * sv));
                hrow[col] = (unsigned short)f2bf((g / (1.f + __expf(-g))) * u);
            }
        }
    }
}

// ---------------- down-proj: 256x256 tile, 8 waves, 2-phase dbuf ----------------
// grid (8, DIM/256=8, 9), block 512; routed -> rb (bf16), shared -> out (fp32)
__global__ __launch_bounds__(512) void down_kernel(
    const unsigned short* __restrict__ h2g,
    const unsigned short* __restrict__ w2b, const unsigned short* __restrict__ sw2b,
    const int* __restrict__ gcnt, const int* __restrict__ gbase,
    unsigned short* __restrict__ rb, float* __restrict__ out)
{
    const int e = blockIdx.z;
    int cnt, base;
    const unsigned short* w2e;
    if (e < NEXP) {
        cnt = gcnt[e];
        if ((int)blockIdx.x * 256 >= cnt) return;
        base = gbase[e];
        w2e = w2b + (size_t)e * DIM * HID;
    } else {
        cnt = NTOK; base = SHBASE; w2e = sw2b;
    }
    const int m0 = blockIdx.x * 256, n0 = blockIdx.y * 256;

    __shared__ char lds[131072];   // dbuf: [A 32K | B 32K] x2

    const int t = threadIdx.x;
    const int lane = t & 63, wv = t >> 6;
    const int wm = wv >> 2, wn = wv & 3;      // 2x4 wave grid
    const int lr = lane & 15, hi = lane >> 4;

    const int scol = ((t & 7) << 4);
    const char* aS[4]; const char* bS[4];
#pragma unroll
    for (int p = 0; p < 4; ++p) {
        int r = p * 64 + (t >> 3);
        aS[p] = (const char*)h2g + (size_t)(base + m0 + r) * (HID * 2) + (scol ^ ((r & 7) << 4));
        bS[p] = (const char*)w2e + (size_t)(n0 + r) * (HID * 2) + (scol ^ ((r & 7) << 4));
    }

    f32x4 acc[8][4];
    const f32x4 zz = {0.f, 0.f, 0.f, 0.f};
#pragma unroll
    for (int m = 0; m < 8; ++m)
#pragma unroll
        for (int n = 0; n < 4; ++n) acc[m][n] = zz;

    auto STAGE = [&](int bo, int kb) {
#pragma unroll
        for (int p = 0; p < 4; ++p) {
            gload16(aS[p] + kb, lds + bo + p * 8192 + wv * 1024);
            gload16(bS[p] + kb, lds + bo + 32768 + p * 8192 + wv * 1024);
        }
    };

    int bo = 0;
    STAGE(0, 0);
    __syncthreads();
    for (int it = 0; it < 16; ++it) {
        if (it < 15) STAGE(bo ^ 65536, (it + 1) * 128);
        const char* A = lds + bo;
        const char* B = A + 32768;
#pragma unroll
        for (int kk = 0; kk < 2; ++kk) {
            bf16x8 af[8], bfr[4];
            const int cb = kk * 64 + hi * 16;
#pragma unroll
            for (int m = 0; m < 8; ++m) {
                int row = wm * 128 + m * 16 + lr;
                af[m] = *reinterpret_cast<const bf16x8*>(A + row * 128 + (cb ^ ((row & 7) << 4)));
            }
#pragma unroll
            for (int n = 0; n < 4; ++n) {
                int row = wn * 64 + n * 16 + lr;
                bfr[n] = *reinterpret_cast<const bf16x8*>(B + row * 128 + (cb ^ ((row & 7) << 4)));
            }
#pragma unroll
            for (int m = 0; m < 8; ++m)
#pragma unroll
                for (int n = 0; n < 4; ++n)
                    acc[m][n] = MFMA(af[m], bfr[n], acc[m][n], 0, 0, 0);
        }
        __syncthreads();
        bo ^= 65536;
    }

#pragma unroll
    for (int m = 0; m < 8; ++m)
#pragma unroll
        for (int r = 0; r < 4; ++r) {
            int row = wm * 128 + m * 16 + hi * 4 + r;
            if (e < NEXP) {
                unsigned short* rrow = rb + (size_t)(base + m0 + row) * DIM + n0 + wn * 64;
#pragma unroll
                for (int n = 0; n < 4; ++n)
                    rrow[n * 16 + lr] = (unsigned short)f2bf(acc[m][n][r]);
            } else {
                float* orow = out + (size_t)(m0 + row) * DIM + n0 + wn * 64;
#pragma unroll
                for (int n = 0; n < 4; ++n)
                    orow[n * 16 + lr] = acc[m][n][r];
            }
        }
}

// ---------------- combine: out(tok) += rb(row1) + rb(row2) ----------------
__global__ __launch_bounds__(256) void combine_kernel(
    const int* __restrict__ rows, const unsigned short* __restrict__ rb,
    float* __restrict__ out)
{
    int i = blockIdx.x * 256 + threadIdx.x;
    int tok = i >> 8, g = i & 255;
    int r1 = rows[tok * 2], r2 = rows[tok * 2 + 1];
    float4* op = reinterpret_cast<float4*>(out + (size_t)tok * DIM + g * 8);
    int4 a = *reinterpret_cast<const int4*>(rb + (size_t)r1 * DIM + g * 8);
    int4 b = *reinterpret_cast<const int4*>(rb + (size_t)r2 * DIM + g * 8);
    float4 o0 = op[0], o1 = op[1];
    o0.x += bf2f((unsigned)a.x & 0xFFFF) + bf2f((unsigned)b.x & 0xFFFF);
    o0.y += bf2f((unsigned)a.x >> 16)    + bf2f((unsigned)b.x >> 16);
    o0.z += bf2f((unsigned)a.y & 0xFFFF) + bf2f((unsigned)b.y & 0xFFFF);
    o0.w += bf2f((unsigned)a.y >> 16)    + bf2f((unsigned)b.y >> 16);
    o1.x += bf2f((unsigned)a.z & 0xFFFF) + bf2f((unsigned)b.z & 0xFFFF);
    o1.y += bf2f((unsigned)a.z >> 16)    + bf2f((unsigned)b.z >> 16);
    o1.z += bf2f((unsigned)a.w & 0xFFFF) + bf2f((unsigned)b.w & 0xFFFF);
    o1.w += bf2f((unsigned)a.w >> 16)    + bf2f((unsigned)b.w >> 16);
    op[0] = o0; op[1] = o1;
}

extern "C" void kernel_launch(void* const* d_in, const int* in_sizes, int n_in,
                              void* d_out, int out_size, void* d_ws, size_t ws_size,
                              hipStream_t stream) {
    const float* x    = (const float*)d_in[0];
    const float* gate = (const float*)d_in[1];
    const float* bias = (const float*)d_in[2];
    const float* w1   = (const float*)d_in[3];
    const float* w2   = (const float*)d_in[4];
    const float* w3   = (const float*)d_in[5];
    const float* sw1  = (const float*)d_in[6];
    const float* sw2  = (const float*)d_in[7];
    const float* sw3  = (const float*)d_in[8];
    float* out = (float*)d_out;

    char* ws = (char*)d_ws;
    size_t o = 0;
    unsigned short* xb   = (unsigned short*)(ws + o); o += 8388608;    // 2048x2048 bf16
    unsigned short* w1b  = (unsigned short*)(ws + o); o += 33554432;
    unsigned short* w3b  = (unsigned short*)(ws + o); o += 33554432;
    unsigned short* w2b  = (unsigned short*)(ws + o); o += 33554432;
    unsigned short* sw1b = (unsigned short*)(ws + o); o += 4194304;
    unsigned short* sw3b = (unsigned short*)(ws + o); o += 4194304;
    unsigned short* sw2b = (unsigned short*)(ws + o); o += 4194304;
    unsigned short* h2g  = (unsigned short*)(ws + o); o += 16777216;   // 8192x1024 bf16
    unsigned short* rb   = (unsigned short*)(ws + o); o += 25165824;   // 6144x2048 bf16
    float* sc            = (float*)(ws + o);          o += 65536;
    int* top2            = (int*)(ws + o);            o += 16384;
    int* tid             = (int*)(ws + o);            o += 65536;
    int* rows            = (int*)(ws + o);            o += 16384;
    int* gcnt            = (int*)(ws + o);            o += 256;
    int* gbase           = (int*)(ws + o);            o += 256;

    cast_kernel<<<4096,  256, 0, stream>>>(x,   xb,   1048576);
    cast_kernel<<<16384, 256, 0, stream>>>(w1,  w1b,  4194304);
    cast_kernel<<<16384, 256, 0, stream>>>(w3,  w3b,  4194304);
    cast_kernel<<<16384, 256, 0, stream>>>(w2,  w2b,  4194304);
    cast_kernel<<<2048,  256, 0, stream>>>(sw1, sw1b, 524288);
    cast_kernel<<<2048,  256, 0, stream>>>(sw3, sw3b, 524288);
    cast_kernel<<<2048,  256, 0, stream>>>(sw2, sw2b, 524288);
    router_kernel<<<2048, 256, 0, stream>>>(x, gate, bias, sc, top2);
    lists_kernel<<<1, 256, 0, stream>>>(top2, gcnt, gbase, tid, rows);
    up_kernel<<<dim3(8, 8, 9), 512, 0, stream>>>(xb, w1b, w3b, sw1b, sw3b, sc, gcnt, gbase, tid, h2g);
    down_kernel<<<dim3(8, 8, 9), 512, 0, stream>>>(h2g, w2b, sw2b, gcnt, gbase, rb, out);
    combine_kernel<<<2048, 256, 0, stream>>>(rows, rb, out);
}